// Round 18
// baseline (145.914 us; speedup 1.0000x reference)
//
#include <hip/hip_runtime.h>

#define NN 50000
#define NE 800000
#define KIN 512
#define HC 128
#define MAXDEG 64
#define NPX 6250                     // nodes per XCD partition (NN/8)
#define ESTRIDE (66 * 256)           // edge-scan stride (66 blocks/xcd * 256)

typedef float f32x4 __attribute__((ext_vector_type(4)));
typedef float f32x2 __attribute__((ext_vector_type(2)));
typedef short s16x8 __attribute__((ext_vector_type(8)));

__device__ __forceinline__ ushort f2bf(float f) {
  unsigned u = __float_as_uint(f);
  unsigned r = (u + 0x7FFFu + ((u >> 16) & 1u)) >> 16;  // RNE
  return (ushort)r;
}

// async global->LDS, 16B per lane, dest = wave-uniform base + lane*16
__device__ __forceinline__ void gload_lds16(const void* g, void* l) {
  __builtin_amdgcn_global_load_lds((const __attribute__((address_space(1))) void*)g,
                                   (__attribute__((address_space(3))) void*)l, 16, 0, 0);
}

// JAX threefry2x32-20, partitionable path: ctr=(0,i), key=(0,42), bits=o0^o1
__device__ __forceinline__ unsigned tf_bits(unsigned i) {
  unsigned x0 = 0u, x1 = i;
  const unsigned ks0 = 0u, ks1 = 42u, ks2 = 0x1BD11BDAu ^ 42u;
#define R(r) { x0 += x1; x1 = (x1 << r) | (x1 >> (32 - r)); x1 ^= x0; }
  x0 += ks0; x1 += ks1;
  R(13) R(15) R(26) R(6)
  x0 += ks1; x1 += ks2 + 1u;
  R(17) R(29) R(16) R(24)
  x0 += ks2; x1 += ks0 + 2u;
  R(13) R(15) R(26) R(6)
  x0 += ks0; x1 += ks1 + 3u;
  R(17) R(29) R(16) R(24)
  x0 += ks1; x1 += ks2 + 4u;
  R(13) R(15) R(26) R(6)
  x0 += ks2; x1 += ks0 + 5u;
#undef R
  return x0 ^ x1;
}

// Wt transpose/convert + zero slots (incl. sentinel slots[NN]=0)
__global__ void k_prep(const float* __restrict__ W, ushort* __restrict__ Wt,
                       int* __restrict__ slots) {
  int t = blockIdx.x * 256 + threadIdx.x;   // 65536 threads
  if (t <= NN) slots[t] = 0;
  if (t < KIN * HC) {
    int c = t & (HC - 1), k = t >> 7;       // W row-major [k][c]
    Wt[c * KIN + k] = f2bf(W[t]);
  }
}

// Fused GEMM + edge pass, XCD-aware roles:
//  edge role ((bid&31)<8): block's xcd=bid&7 handles ONLY dst in its 6250-node
//  partition -> slots atomics + csr16 lines stay in ONE XCD's L2 (no cross-XCD
//  RMW ping-pong). Scans all edges with coalesced strided d-reads (L3-shared).
//  gemm role: xb = feats @ W unscaled bf16 (rows>=NN zero sentinel) + computes
//  this tile's 512 dropout-mask bytes at full lane efficiency (hides in stalls).
__launch_bounds__(256, 6)
__global__ void k_bg(const float* __restrict__ feats, const ushort* __restrict__ Wt,
                     ushort* __restrict__ xb, const int* __restrict__ ei,
                     int* __restrict__ slots, unsigned char* __restrict__ mask,
                     ushort* __restrict__ csr16) {
  if ((blockIdx.x & 31) < 8) {              // ---- edge role: 528 blocks ----
    const int xcd = blockIdx.x & 7;
    const int eb  = blockIdx.x >> 5;        // 0..65 within xcd
    const int dlo = xcd * NPX, dhi = dlo + NPX;
    const int e0 = eb * 256 + threadIdx.x;
#pragma unroll 4
    for (int it = 0; it < 48; ++it) {
      int e = e0 + it * ESTRIDE;
      if (e < NE) {
        int d = ei[NE + e];                 // coalesced across the wave
        if (d >= dlo && d < dhi) {          // ~1/8 lanes; short mem-op body
          int s = ei[e];
          int slot = atomicAdd(&slots[d], 1);     // XCD-local L2 atomic
          if (slot < MAXDEG) csr16[d * MAXDEG + slot] = (ushort)s;
        }
      }
    }
    return;
  }
  // ---- gemm role: 1584 slots -> 1563 tiles, 32x128, 4 waves 2x2 ----
  const int g = (blockIdx.x >> 5) * 24 + (blockIdx.x & 31) - 8;
  if (g >= 1563) return;                    // whole block exits (no barrier yet)
  __shared__ __align__(16) float  As[32 * 64];    // 8 KB, 256 B/row (16 chunks)
  __shared__ __align__(16) ushort Bs[128 * 64];   // 16 KB, 128 B/row (8 chunks)
  const int tid = threadIdx.x;
  const int lane = tid & 63;
  const int w = tid >> 6;
  const int wm = w >> 1, wn = w & 1;
  const int rbase = g * 32;                       // rows 0..50015

  // dropout-mask bytes for this tile's rows (full-lane threefry; VALU hides
  // under the K-loop's staging stalls after scheduling)
  {
    int mb = rbase * 16 + tid;
#pragma unroll
    for (int h = 0; h < 2; ++h, mb += 256) {
      if (mb < NN * 16) {
        unsigned by = 0;
#pragma unroll
        for (int k = 0; k < 8; k++)
          by |= (tf_bits(8u * (unsigned)mb + k) >> 31) << k;   // bit=1 -> drop
        mask[mb] = (unsigned char)by;
      }
    }
  }

  f32x4 acc[4];
#pragma unroll
  for (int nt = 0; nt < 4; nt++) acc[nt] = f32x4{0.f, 0.f, 0.f, 0.f};

  const int a_rt = w * 8 + (lane >> 4);
  int a_gr[2];
#pragma unroll
  for (int i = 0; i < 2; i++) {
    int gr = rbase + a_rt + i * 4;
    a_gr[i] = (gr < NN) ? gr : NN - 1;
  }
  const int b_ct = w * 32 + (lane >> 3);              // + i*8 ; B tile col (Wt row)
  const int b_ch = ((lane & 7) ^ (b_ct & 7)) << 3;    // bf16 offset of swizzled chunk

  for (int ks = 0; ks < KIN; ks += 64) {
    __syncthreads();                               // prev-step LDS reads done
#pragma unroll
    for (int i = 0; i < 2; i++) {
      // A dest row ar = a_rt + i*4 -> (ar&7) = (a_rt&7) ^ ((i&1)<<2)
      int a_ch = ((lane & 15) ^ (a_rt & 7) ^ ((i & 1) << 2)) << 2;   // f32 offset
      gload_lds16(feats + (size_t)a_gr[i] * KIN + ks + a_ch,
                  (char*)As + (w * 8 + i * 4) * 256);
    }
#pragma unroll
    for (int i = 0; i < 4; i++)
      gload_lds16(Wt + (size_t)(b_ct + i * 8) * KIN + ks + b_ch,
                  (char*)Bs + (w * 32 + i * 8) * 128);
    __syncthreads();                               // staged (vmcnt drained by barrier)
#pragma unroll
    for (int kk = 0; kk < 2; kk++) {
      s16x8 bfr[4];
#pragma unroll
      for (int nt = 0; nt < 4; nt++) {
        int c = wn * 64 + nt * 16 + (lane & 15);
        int ch = (kk * 4 + (lane >> 4)) ^ (c & 7);
        bfr[nt] = *(const s16x8*)((const char*)Bs + c * 128 + ch * 16);
      }
      int r = wm * 16 + (lane & 15);
      int c0 = kk * 8 + (lane >> 4) * 2;
      f32x4 f0 = *(const f32x4*)((const char*)As + r * 256 + ((c0 ^ (r & 7)) * 16));
      f32x4 f1 = *(const f32x4*)((const char*)As + r * 256 + (((c0 + 1) ^ (r & 7)) * 16));
      s16x8 af;
#pragma unroll
      for (int t = 0; t < 4; t++) {
        af[t]     = (short)f2bf(f0[t]);
        af[t + 4] = (short)f2bf(f1[t]);
      }
#pragma unroll
      for (int nt = 0; nt < 4; nt++)
        acc[nt] = __builtin_amdgcn_mfma_f32_16x16x32_bf16(af, bfr[nt], acc[nt], 0, 0, 0);
    }
  }
  // C/D frag: col = lane&15, row = (lane>>4)*4 + j ; rows >= NN -> zero sentinel
  {
    int rb = rbase + wm * 16 + (lane >> 4) * 4;
#pragma unroll
    for (int j = 0; j < 4; j++) {
      int r = rb + j;
      bool ok = (r < NN);
#pragma unroll
      for (int nt = 0; nt < 4; nt++) {
        int c = wn * 64 + nt * 16 + (lane & 15);
        xb[(size_t)r * HC + c] = ok ? f2bf(acc[nt][j]) : (ushort)0;
      }
    }
  }
}

// one wave per node, 4-way edge split: sum of x[src]*dinv[src] with dinv
// computed f32 from L2-hot slots[]; dn + bias + relu + mask after reduce.
// Tail slots gather sentinel row NN (zeros) with slots[NN]=0.
__global__ void k_agg(const ushort* __restrict__ xb, const int* __restrict__ slots,
                      const ushort* __restrict__ csr16,
                      const unsigned char* __restrict__ mask,
                      const float* __restrict__ b, float* __restrict__ out) {
  int n = blockIdx.x * 4 + (threadIdx.x >> 6);
  if (n >= NN) return;
  const int lane = threadIdx.x & 63;
  const int grp = lane >> 4;          // edge slot (0..3)
  const int q = lane & 15;            // channels q*8 .. q*8+7
  const int degt = slots[n];          // true degree
  const int deg = (degt < MAXDEG) ? degt : MAXDEG;
  const float dn = rsqrtf((float)(degt + 1));

  float a0, a1, a2, a3, a4, a5, a6, a7;
  {
    // self term: x[n]*dinv[n], group 0 only (final *dn gives dn^2 norm)
    uint4 sv = *(const uint4*)(xb + (size_t)n * HC + q * 8);
    float z = (grp == 0) ? dn : 0.0f;
    a0 = __uint_as_float(sv.x << 16)         * z;
    a1 = __uint_as_float(sv.x & 0xFFFF0000u) * z;
    a2 = __uint_as_float(sv.y << 16)         * z;
    a3 = __uint_as_float(sv.y & 0xFFFF0000u) * z;
    a4 = __uint_as_float(sv.z << 16)         * z;
    a5 = __uint_as_float(sv.z & 0xFFFF0000u) * z;
    a6 = __uint_as_float(sv.w << 16)         * z;
    a7 = __uint_as_float(sv.w & 0xFFFF0000u) * z;
  }

  const ushort* cp = csr16 + (size_t)n * MAXDEG;
  const int np = (deg + 3) >> 2;      // quads
  unsigned s0 = (grp < deg) ? cp[grp] : (unsigned)NN;   // sentinel = zero row
  uint4 g = *(const uint4*)(xb + (size_t)s0 * HC + q * 8);
  int c0 = slots[s0];
  for (int j = 0; j < np; ++j) {
    int idx = 4 * j + 4 + grp;
    unsigned s1 = (idx < deg) ? cp[idx] : (unsigned)NN;
    uint4 gn = *(const uint4*)(xb + (size_t)s1 * HC + q * 8);
    int c1 = slots[s1];
    float di = rsqrtf((float)(c0 + 1));   // dinv[src], f32 precision
    a0 += __uint_as_float(g.x << 16)         * di;
    a1 += __uint_as_float(g.x & 0xFFFF0000u) * di;
    a2 += __uint_as_float(g.y << 16)         * di;
    a3 += __uint_as_float(g.y & 0xFFFF0000u) * di;
    a4 += __uint_as_float(g.z << 16)         * di;
    a5 += __uint_as_float(g.z & 0xFFFF0000u) * di;
    a6 += __uint_as_float(g.w << 16)         * di;
    a7 += __uint_as_float(g.w & 0xFFFF0000u) * di;
    g = gn; c0 = c1;
  }
  // reduce across the 4 groups
#define RED(A) A += __shfl_xor(A, 16); A += __shfl_xor(A, 32);
  RED(a0) RED(a1) RED(a2) RED(a3) RED(a4) RED(a5) RED(a6) RED(a7)
#undef RED
  // group grp finalizes channels q*8+2*grp, q*8+2*grp+1
  float sx = (grp == 0) ? a0 : (grp == 1) ? a2 : (grp == 2) ? a4 : a6;
  float sy = (grp == 0) ? a1 : (grp == 1) ? a3 : (grp == 2) ? a5 : a7;
  int i0 = n * HC + q * 8 + 2 * grp;
  f32x2 bb = *(const f32x2*)(b + q * 8 + 2 * grp);
  float vx = fmaxf(sx * dn + bb.x, 0.f) * 2.f;
  float vy = fmaxf(sy * dn + bb.y, 0.f) * 2.f;
  unsigned m = mask[n * 16 + q];      // drop bits for elements q*8 .. q*8+7
  f32x2 r;
  r.x = ((m >> (2 * grp))     & 1u) ? 0.f : vx;
  r.y = ((m >> (2 * grp + 1)) & 1u) ? 0.f : vy;
  *(f32x2*)(out + i0) = r;
}

extern "C" void kernel_launch(void* const* d_in, const int* in_sizes, int n_in,
                              void* d_out, int out_size, void* d_ws, size_t ws_size,
                              hipStream_t stream) {
  const float* feats = (const float*)d_in[0];
  const float* W     = (const float*)d_in[1];
  const float* b     = (const float*)d_in[2];
  const int*   ei    = (const int*)d_in[3];
  float* out = (float*)d_out;

  // ws: xb[50016*HC] bf16 | Wt[HC*KIN] bf16 | slots[NN+1] i32 | mask[NE+512] u8 |
  //     csr16[NN*64] u16   (~21 MB)
  char* ws = (char*)d_ws;
  size_t o = 0;
  ushort*        xb    = (ushort*)(ws + o);        o += ((size_t)50016 * HC * 2 + 255) & ~(size_t)255;
  ushort*        Wt    = (ushort*)(ws + o);        o += ((size_t)HC * KIN * 2 + 255) & ~(size_t)255;
  int*           slots = (int*)(ws + o);           o += ((size_t)(NN + 1) * 4 + 255) & ~(size_t)255;
  unsigned char* mask  = (unsigned char*)(ws + o); o += ((size_t)NE + 512 + 255) & ~(size_t)255;
  ushort*        csr16 = (ushort*)(ws + o);

  k_prep<<<256, 256, 0, stream>>>(W, Wt, slots);
  k_bg  <<<2112, 256, 0, stream>>>(feats, Wt, xb, ei, slots, mask, csr16);
  k_agg <<<(NN + 3) / 4, 256, 0, stream>>>(xb, slots, csr16, mask, b, out);
}

// Round 19
// 106.080 us; speedup vs baseline: 1.3755x; 1.3755x over previous
//
#include <hip/hip_runtime.h>

#define NN 50000
#define NE 800000
#define KIN 512
#define HC 128
#define MAXDEG 64
#define NBK 782                      // dst buckets of 64 nodes ((NN+63)/64)

typedef float f32x4 __attribute__((ext_vector_type(4)));
typedef float f32x2 __attribute__((ext_vector_type(2)));
typedef short s16x8 __attribute__((ext_vector_type(8)));

__device__ __forceinline__ ushort f2bf(float f) {
  unsigned u = __float_as_uint(f);
  unsigned r = (u + 0x7FFFu + ((u >> 16) & 1u)) >> 16;  // RNE
  return (ushort)r;
}

__device__ __forceinline__ void gload_lds16(const void* g, void* l) {
  __builtin_amdgcn_global_load_lds((const __attribute__((address_space(1))) void*)g,
                                   (__attribute__((address_space(3))) void*)l, 16, 0, 0);
}

// JAX threefry2x32-20, partitionable path: ctr=(0,i), key=(0,42), bits=o0^o1
__device__ __forceinline__ unsigned tf_bits(unsigned i) {
  unsigned x0 = 0u, x1 = i;
  const unsigned ks0 = 0u, ks1 = 42u, ks2 = 0x1BD11BDAu ^ 42u;
#define R(r) { x0 += x1; x1 = (x1 << r) | (x1 >> (32 - r)); x1 ^= x0; }
  x0 += ks0; x1 += ks1;
  R(13) R(15) R(26) R(6)
  x0 += ks1; x1 += ks2 + 1u;
  R(17) R(29) R(16) R(24)
  x0 += ks2; x1 += ks0 + 2u;
  R(13) R(15) R(26) R(6)
  x0 += ks0; x1 += ks1 + 3u;
  R(17) R(29) R(16) R(24)
  x0 += ks1; x1 += ks2 + 4u;
  R(13) R(15) R(26) R(6)
  x0 += ks2; x1 += ks0 + 5u;
#undef R
  return x0 ^ x1;
}

// Wt transpose/convert + zero the 782 bucket counters
__global__ void k_prep(const float* __restrict__ W, ushort* __restrict__ Wt,
                       int* __restrict__ hist) {
  int t = blockIdx.x * 256 + threadIdx.x;   // 65536 threads
  if (t < NBK) hist[t] = 0;
  if (t < KIN * HC) {
    int c = t & (HC - 1), k = t >> 7;       // W row-major [k][c]
    Wt[c * KIN + k] = f2bf(W[t]);
  }
}

// coarse histogram of dst>>6 (LDS-aggregated; ~306K hot-line global atomics)
__global__ void k_hist(const int* __restrict__ ei, int* __restrict__ hist) {
  __shared__ int h[NBK];
  const int tid = threadIdx.x;
  for (int i = tid; i < NBK; i += 256) h[i] = 0;
  __syncthreads();
  const int base = blockIdx.x * 2048 + tid;
#pragma unroll
  for (int k = 0; k < 8; k++) {
    int e = base + k * 256;
    if (e < NE) atomicAdd(&h[ei[NE + e] >> 6], 1);
  }
  __syncthreads();
  for (int i = tid; i < NBK; i += 256)
    if (h[i]) atomicAdd(&hist[i], h[i]);
}

// exclusive scan of 782 bucket counts -> base[783]; cursors=base; slots[NN]=0
__global__ void k_scan(const int* __restrict__ hist, int* __restrict__ base,
                       int* __restrict__ cursors, int* __restrict__ slots) {
  const int t = threadIdx.x;                // 1024 threads
  const int lane = t & 63, wid = t >> 6;    // 16 waves
  int c = (t < NBK) ? hist[t] : 0;
  int v = c;
#pragma unroll
  for (int d = 1; d < 64; d <<= 1) {
    int u = __shfl_up(v, d);
    if (lane >= d) v += u;
  }
  __shared__ int wsum[16];
  if (lane == 63) wsum[wid] = v;
  __syncthreads();
  int wadd = 0;
#pragma unroll
  for (int w = 0; w < 15; w++) if (w < wid) wadd += wsum[w];
  int excl = v + wadd - c;
  if (t < NBK) { base[t] = excl; cursors[t] = excl; }
  if (t == NBK) base[NBK] = NE;
  if (t == NBK + 1) slots[NN] = 0;          // sentinel
}

// counting-sort scatter: sorted[pos] = (d<<16)|s, pos = gbase[bkt]+lrank
__global__ void k_sort(const int* __restrict__ ei, int* __restrict__ cursors,
                       unsigned* __restrict__ sorted) {
  __shared__ int lcnt[NBK];
  __shared__ int gb[NBK];
  const int tid = threadIdx.x;
  for (int i = tid; i < NBK; i += 256) lcnt[i] = 0;
  __syncthreads();
  const int base = blockIdx.x * 2048 + tid;
  int bk[8], lr[8]; unsigned pk[8];
#pragma unroll
  for (int k = 0; k < 8; k++) {
    int e = base + k * 256;
    bk[k] = -1;
    if (e < NE) {
      int s = ei[e], d = ei[NE + e];
      pk[k] = ((unsigned)d << 16) | (unsigned)s;
      bk[k] = d >> 6;
      lr[k] = atomicAdd(&lcnt[bk[k]], 1);
    }
  }
  __syncthreads();
  for (int i = tid; i < NBK; i += 256)
    if (lcnt[i]) gb[i] = atomicAdd(&cursors[i], lcnt[i]);
  __syncthreads();
#pragma unroll
  for (int k = 0; k < 8; k++)
    if (bk[k] >= 0) sorted[gb[bk[k]] + lr[k]] = pk[k];
}

// CSR build, one block per bucket: LDS slot counters (no global atomics);
// csr16 window (8 KB) is block-exclusive -> burst-dense stores.
__global__ void k_csr(const unsigned* __restrict__ sorted, const int* __restrict__ base,
                      ushort* __restrict__ csr16, int* __restrict__ slots) {
  __shared__ int lc[64];
  const int b = blockIdx.x;                 // 0..781
  const int tid = threadIdx.x;
  if (tid < 64) lc[tid] = 0;
  __syncthreads();
  const int lo = base[b], hi = base[b + 1];
  for (int i = lo + tid; i < hi; i += 256) {
    unsigned u = sorted[i];
    int d = u >> 16, s = u & 0xFFFFu;
    int slot = atomicAdd(&lc[d & 63], 1);
    if (slot < MAXDEG) csr16[(size_t)d * MAXDEG + slot] = (ushort)s;
  }
  __syncthreads();
  if (tid < 64) {
    int n = b * 64 + tid;
    if (n < NN) slots[n] = lc[tid];         // true degree
  }
}

// xb = feats @ W unscaled bf16 (rows>=NN zero sentinel) + dropout-mask bytes
// for this tile's rows (full-lane threefry hidden under staging stalls).
__launch_bounds__(256, 6)
__global__ void k_gemm(const float* __restrict__ feats, const ushort* __restrict__ Wt,
                       ushort* __restrict__ xb, unsigned char* __restrict__ mask) {
  __shared__ __align__(16) float  As[32 * 64];    // 8 KB, 256 B/row (16 chunks)
  __shared__ __align__(16) ushort Bs[128 * 64];   // 16 KB, 128 B/row (8 chunks)
  const int tid = threadIdx.x;
  const int lane = tid & 63;
  const int w = tid >> 6;
  const int wm = w >> 1, wn = w & 1;
  const int rbase = blockIdx.x * 32;              // 1563 blocks -> rows 0..50015

  {
    int mb = rbase * 16 + tid;
#pragma unroll
    for (int h = 0; h < 2; ++h, mb += 256) {
      if (mb < NN * 16) {
        unsigned by = 0;
#pragma unroll
        for (int k = 0; k < 8; k++)
          by |= (tf_bits(8u * (unsigned)mb + k) >> 31) << k;   // bit=1 -> drop
        mask[mb] = (unsigned char)by;
      }
    }
  }

  f32x4 acc[4];
#pragma unroll
  for (int nt = 0; nt < 4; nt++) acc[nt] = f32x4{0.f, 0.f, 0.f, 0.f};

  const int a_rt = w * 8 + (lane >> 4);
  int a_gr[2];
#pragma unroll
  for (int i = 0; i < 2; i++) {
    int gr = rbase + a_rt + i * 4;
    a_gr[i] = (gr < NN) ? gr : NN - 1;
  }
  const int b_ct = w * 32 + (lane >> 3);              // + i*8 ; B tile col (Wt row)
  const int b_ch = ((lane & 7) ^ (b_ct & 7)) << 3;    // bf16 offset of swizzled chunk

  for (int ks = 0; ks < KIN; ks += 64) {
    __syncthreads();                               // prev-step LDS reads done
#pragma unroll
    for (int i = 0; i < 2; i++) {
      // A dest row ar = a_rt + i*4 -> (ar&7) = (a_rt&7) ^ ((i&1)<<2)
      int a_ch = ((lane & 15) ^ (a_rt & 7) ^ ((i & 1) << 2)) << 2;   // f32 offset
      gload_lds16(feats + (size_t)a_gr[i] * KIN + ks + a_ch,
                  (char*)As + (w * 8 + i * 4) * 256);
    }
#pragma unroll
    for (int i = 0; i < 4; i++)
      gload_lds16(Wt + (size_t)(b_ct + i * 8) * KIN + ks + b_ch,
                  (char*)Bs + (w * 32 + i * 8) * 128);
    __syncthreads();                               // staged (vmcnt drained by barrier)
#pragma unroll
    for (int kk = 0; kk < 2; kk++) {
      s16x8 bfr[4];
#pragma unroll
      for (int nt = 0; nt < 4; nt++) {
        int c = wn * 64 + nt * 16 + (lane & 15);
        int ch = (kk * 4 + (lane >> 4)) ^ (c & 7);
        bfr[nt] = *(const s16x8*)((const char*)Bs + c * 128 + ch * 16);
      }
      int r = wm * 16 + (lane & 15);
      int c0 = kk * 8 + (lane >> 4) * 2;
      f32x4 f0 = *(const f32x4*)((const char*)As + r * 256 + ((c0 ^ (r & 7)) * 16));
      f32x4 f1 = *(const f32x4*)((const char*)As + r * 256 + (((c0 + 1) ^ (r & 7)) * 16));
      s16x8 af;
#pragma unroll
      for (int t = 0; t < 4; t++) {
        af[t]     = (short)f2bf(f0[t]);
        af[t + 4] = (short)f2bf(f1[t]);
      }
#pragma unroll
      for (int nt = 0; nt < 4; nt++)
        acc[nt] = __builtin_amdgcn_mfma_f32_16x16x32_bf16(af, bfr[nt], acc[nt], 0, 0, 0);
    }
  }
  // C/D frag: col = lane&15, row = (lane>>4)*4 + j ; rows >= NN -> zero sentinel
  {
    int rb = rbase + wm * 16 + (lane >> 4) * 4;
#pragma unroll
    for (int j = 0; j < 4; j++) {
      int r = rb + j;
      bool ok = (r < NN);
#pragma unroll
      for (int nt = 0; nt < 4; nt++) {
        int c = wn * 64 + nt * 16 + (lane & 15);
        xb[(size_t)r * HC + c] = ok ? f2bf(acc[nt][j]) : (ushort)0;
      }
    }
  }
}

// one wave per node, 4-way edge split: sum of x[src]*dinv[src], dinv f32 from
// L2-hot slots[]; dn + bias + relu + mask after reduce. Sentinel row NN = 0.
__global__ void k_agg(const ushort* __restrict__ xb, const int* __restrict__ slots,
                      const ushort* __restrict__ csr16,
                      const unsigned char* __restrict__ mask,
                      const float* __restrict__ b, float* __restrict__ out) {
  int n = blockIdx.x * 4 + (threadIdx.x >> 6);
  if (n >= NN) return;
  const int lane = threadIdx.x & 63;
  const int grp = lane >> 4;          // edge slot (0..3)
  const int q = lane & 15;            // channels q*8 .. q*8+7
  const int degt = slots[n];          // true degree
  const int deg = (degt < MAXDEG) ? degt : MAXDEG;
  const float dn = rsqrtf((float)(degt + 1));

  float a0, a1, a2, a3, a4, a5, a6, a7;
  {
    // self term: x[n]*dinv[n], group 0 only (final *dn gives dn^2 norm)
    uint4 sv = *(const uint4*)(xb + (size_t)n * HC + q * 8);
    float z = (grp == 0) ? dn : 0.0f;
    a0 = __uint_as_float(sv.x << 16)         * z;
    a1 = __uint_as_float(sv.x & 0xFFFF0000u) * z;
    a2 = __uint_as_float(sv.y << 16)         * z;
    a3 = __uint_as_float(sv.y & 0xFFFF0000u) * z;
    a4 = __uint_as_float(sv.z << 16)         * z;
    a5 = __uint_as_float(sv.z & 0xFFFF0000u) * z;
    a6 = __uint_as_float(sv.w << 16)         * z;
    a7 = __uint_as_float(sv.w & 0xFFFF0000u) * z;
  }

  const ushort* cp = csr16 + (size_t)n * MAXDEG;
  const int np = (deg + 3) >> 2;      // quads
  unsigned s0 = (grp < deg) ? cp[grp] : (unsigned)NN;   // sentinel = zero row
  uint4 g = *(const uint4*)(xb + (size_t)s0 * HC + q * 8);
  int c0 = slots[s0];
  for (int j = 0; j < np; ++j) {
    int idx = 4 * j + 4 + grp;
    unsigned s1 = (idx < deg) ? cp[idx] : (unsigned)NN;
    uint4 gn = *(const uint4*)(xb + (size_t)s1 * HC + q * 8);
    int c1 = slots[s1];
    float di = rsqrtf((float)(c0 + 1));   // dinv[src], f32 precision
    a0 += __uint_as_float(g.x << 16)         * di;
    a1 += __uint_as_float(g.x & 0xFFFF0000u) * di;
    a2 += __uint_as_float(g.y << 16)         * di;
    a3 += __uint_as_float(g.y & 0xFFFF0000u) * di;
    a4 += __uint_as_float(g.z << 16)         * di;
    a5 += __uint_as_float(g.z & 0xFFFF0000u) * di;
    a6 += __uint_as_float(g.w << 16)         * di;
    a7 += __uint_as_float(g.w & 0xFFFF0000u) * di;
    g = gn; c0 = c1;
  }
#define RED(A) A += __shfl_xor(A, 16); A += __shfl_xor(A, 32);
  RED(a0) RED(a1) RED(a2) RED(a3) RED(a4) RED(a5) RED(a6) RED(a7)
#undef RED
  float sx = (grp == 0) ? a0 : (grp == 1) ? a2 : (grp == 2) ? a4 : a6;
  float sy = (grp == 0) ? a1 : (grp == 1) ? a3 : (grp == 2) ? a5 : a7;
  int i0 = n * HC + q * 8 + 2 * grp;
  f32x2 bb = *(const f32x2*)(b + q * 8 + 2 * grp);
  float vx = fmaxf(sx * dn + bb.x, 0.f) * 2.f;
  float vy = fmaxf(sy * dn + bb.y, 0.f) * 2.f;
  unsigned m = mask[n * 16 + q];      // drop bits for elements q*8 .. q*8+7
  f32x2 r;
  r.x = ((m >> (2 * grp))     & 1u) ? 0.f : vx;
  r.y = ((m >> (2 * grp + 1)) & 1u) ? 0.f : vy;
  *(f32x2*)(out + i0) = r;
}

extern "C" void kernel_launch(void* const* d_in, const int* in_sizes, int n_in,
                              void* d_out, int out_size, void* d_ws, size_t ws_size,
                              hipStream_t stream) {
  const float* feats = (const float*)d_in[0];
  const float* W     = (const float*)d_in[1];
  const float* b     = (const float*)d_in[2];
  const int*   ei    = (const int*)d_in[3];
  float* out = (float*)d_out;

  // ws: xb[50016*HC] bf16 | Wt[HC*KIN] bf16 | slots[NN+1] i32 | mask[NE+512] u8
  //   | csr16[NN*64] u16 | hist[NBK] | base[NBK+1] | cursors[NBK] | sorted[NE] u32
  char* ws = (char*)d_ws;
  size_t o = 0;
  ushort*        xb      = (ushort*)(ws + o);        o += ((size_t)50016 * HC * 2 + 255) & ~(size_t)255;
  ushort*        Wt      = (ushort*)(ws + o);        o += ((size_t)HC * KIN * 2 + 255) & ~(size_t)255;
  int*           slots   = (int*)(ws + o);           o += ((size_t)(NN + 1) * 4 + 255) & ~(size_t)255;
  unsigned char* mask    = (unsigned char*)(ws + o); o += ((size_t)NE + 512 + 255) & ~(size_t)255;
  ushort*        csr16   = (ushort*)(ws + o);        o += ((size_t)NN * MAXDEG * 2 + 255) & ~(size_t)255;
  int*           hist    = (int*)(ws + o);           o += ((size_t)NBK * 4 + 255) & ~(size_t)255;
  int*           baseArr = (int*)(ws + o);           o += ((size_t)(NBK + 1) * 4 + 255) & ~(size_t)255;
  int*           cursors = (int*)(ws + o);           o += ((size_t)NBK * 4 + 255) & ~(size_t)255;
  unsigned*      sorted  = (unsigned*)(ws + o);

  k_prep<<<256, 256, 0, stream>>>(W, Wt, hist);
  k_hist<<<(NE + 2047) / 2048, 256, 0, stream>>>(ei, hist);
  k_scan<<<1, 1024, 0, stream>>>(hist, baseArr, cursors, slots);
  k_sort<<<(NE + 2047) / 2048, 256, 0, stream>>>(ei, cursors, sorted);
  k_csr <<<NBK, 256, 0, stream>>>(sorted, baseArr, csr16, slots);
  k_gemm<<<(NN + 31) / 32, 256, 0, stream>>>(feats, Wt, xb, mask);
  k_agg <<<(NN + 3) / 4, 256, 0, stream>>>(xb, slots, csr16, mask, b, out);
}